// Round 3
// baseline (2365.029 us; speedup 1.0000x reference)
//
#include <hip/hip_runtime.h>

#define HW 512
#define NPIX (HW*HW)
#define NSAMP 64
#define KSEL 2621
#define TILE 64
#define NF 3
#define NQ (NF*NSAMP)
#define CAP 16384

// ===========================================================================
// Shared conv helpers: 64x64 tile staged with halo 3 (max filter), 16 outputs
// per thread. OFF recenters smaller filters inside the halo-3 tile.
// ===========================================================================
template<int K>
__device__ __forceinline__ void conv16_f64(
    const float (*xt)[TILE + 8], const double* __restrict__ wsm,
    int tx, int ty0, double* __restrict__ acc)
{
  constexpr int OFF = 3 - K/2;
  #pragma unroll
  for (int j = 0; j < K; ++j) {
    double dcol[16 + K - 1];
    #pragma unroll
    for (int y = 0; y < 16 + K - 1; ++y)
      dcol[y] = (double)xt[ty0 + y + OFF][tx + j + OFF];
    #pragma unroll
    for (int i = 0; i < K; ++i) {
      const double wv = wsm[i*K + j];
      #pragma unroll
      for (int r = 0; r < 16; ++r)
        acc[r] = fma(dcol[r + i], wv, acc[r]);
    }
  }
}

template<int K>
__device__ __forceinline__ void conv16_f32(
    const float (*xt)[TILE + 8], const float* __restrict__ wsm,
    int tx, int ty0, float* __restrict__ acc)
{
  constexpr int OFF = 3 - K/2;
  #pragma unroll
  for (int j = 0; j < K; ++j) {
    float col[16 + K - 1];
    #pragma unroll
    for (int y = 0; y < 16 + K - 1; ++y)
      col[y] = xt[ty0 + y + OFF][tx + j + OFF];
    #pragma unroll
    for (int i = 0; i < K; ++i) {
      const float wv = wsm[i*K + j];
      #pragma unroll
      for (int r = 0; r < 16; ++r)
        acc[r] = fmaf(col[r + i], wv, acc[r]);
    }
  }
}

// ===========================================================================
// FUSED PATH (needs ~217 MB ws)
// ===========================================================================

// Forward: stage x tile once, compute sim3/sim5/sim7 (fp64), level-1 hist
// (bits[30:20], 2048 bins) per filter. q = f*NSAMP + s.
__global__ __launch_bounds__(256) void fwd_all(
    const float* __restrict__ x,
    const float* __restrict__ w3, const float* __restrict__ w5,
    const float* __restrict__ w7,
    float* __restrict__ sims, unsigned* __restrict__ hist1)
{
  constexpr int P = 3, TW = TILE + 2*P, TWP = TW + 2;
  __shared__ float xt[TW][TWP];
  __shared__ double wsm[49];
  __shared__ unsigned lh[2048];

  const int tid = threadIdx.x;
  const int s  = blockIdx.z;
  const int bx = blockIdx.x * TILE, by = blockIdx.y * TILE;
  const float* __restrict__ xs = x + (size_t)s*NPIX;

  for (int idx = tid; idx < TW*TW; idx += 256) {
    const int r = idx / TW, c = idx % TW;
    const int gy = by + r - P, gx = bx + c - P;
    float v = 0.0f;
    if (gy >= 0 && gy < HW && gx >= 0 && gx < HW) v = xs[gy*HW + gx];
    xt[r][c] = v;
  }

  const int tx  = tid & 63;
  const int ty0 = (tid >> 6) * 16;
  const float* const wp[NF] = {w3, w5, w7};

  #pragma unroll
  for (int f = 0; f < NF; ++f) {
    const int K = 3 + 2*f;
    __syncthreads();                       // xt ready / prev merge complete
    if (tid < K*K) wsm[tid] = (double)wp[f][tid];
    for (int i = tid; i < 2048; i += 256) lh[i] = 0;
    __syncthreads();

    double acc[16];
    #pragma unroll
    for (int r = 0; r < 16; ++r) acc[r] = 0.0;
    if (K == 3)      conv16_f64<3>(xt, wsm, tx, ty0, acc);
    else if (K == 5) conv16_f64<5>(xt, wsm, tx, ty0, acc);
    else             conv16_f64<7>(xt, wsm, tx, ty0, acc);

    float* __restrict__ so =
        sims + ((size_t)f*NSAMP + s)*NPIX + (size_t)by*HW + bx;
    #pragma unroll
    for (int r = 0; r < 16; ++r) {
      const float sv = (float)acc[r];
      so[(size_t)(ty0 + r)*HW + tx] = sv;
      const unsigned bits = __float_as_uint(sv) & 0x7fffffffu;
      atomicAdd(&lh[bits >> 20], 1u);
    }
    __syncthreads();
    unsigned* __restrict__ gh = hist1 + ((size_t)f*NSAMP + s)*2048;
    for (int i = tid; i < 2048; i += 256) {
      const unsigned c = lh[i];
      if (c) atomicAdd(&gh[i], c);
    }
  }
}

// Level-1 scan: one block per q. Picks level-1 bin, writes prefix/krem.
__global__ __launch_bounds__(256) void scan1_all(
    const unsigned* __restrict__ hist1, unsigned* __restrict__ prefix1,
    unsigned* __restrict__ krem1)
{
  const int q = blockIdx.x;
  const int t = threadIdx.x;
  const unsigned* __restrict__ h = hist1 + (size_t)q*2048;
  __shared__ unsigned part[256];
  unsigned sum = 0;
  #pragma unroll
  for (int i = 0; i < 8; ++i) sum += h[t*8 + i];
  part[t] = sum;
  __syncthreads();
  if (t == 0) {
    const unsigned kr = KSEL;
    unsigned cum = 0; int sc = 0;
    for (int c = 255; c >= 0; --c) {
      if (cum + part[c] >= kr) { sc = c; break; }
      cum += part[c];
    }
    unsigned cum2 = cum; int sb = sc*8;
    for (int b = sc*8 + 7; b >= sc*8; --b) {
      if (cum2 + h[b] >= kr) { sb = b; break; }
      cum2 += h[b];
    }
    prefix1[q] = ((unsigned)sb) << 20;
    krem1[q]   = kr - cum2;
  }
}

// Level-2: one pass over all sims. Hist of bits[19:9] among level-1-bin
// matches; compact matching bit-patterns into cand[q] (cap + fallback flag
// via cnt > CAP).
__global__ __launch_bounds__(256) void refine2_all(
    const float* __restrict__ sims, const unsigned* __restrict__ prefix1,
    unsigned* __restrict__ hist2, unsigned* __restrict__ cnt,
    unsigned* __restrict__ cand)
{
  __shared__ unsigned lh[2048];
  const int tid = threadIdx.x;
  const int q = blockIdx.y;
  for (int i = tid; i < 2048; i += 256) lh[i] = 0;
  __syncthreads();

  const unsigned pb = prefix1[q] >> 20;
  const float4* __restrict__ p =
      (const float4*)(sims + (size_t)q*NPIX) + (size_t)blockIdx.x*1024;
  #pragma unroll
  for (int k = 0; k < 4; ++k) {
    const float4 v = p[k*256 + tid];
    const float f4[4] = {v.x, v.y, v.z, v.w};
    #pragma unroll
    for (int e = 0; e < 4; ++e) {
      const unsigned bits = __float_as_uint(f4[e]) & 0x7fffffffu;
      if ((bits >> 20) == pb) {
        atomicAdd(&lh[(bits >> 9) & 0x7ffu], 1u);
        const unsigned pos = atomicAdd(&cnt[q], 1u);
        if (pos < CAP) cand[(size_t)q*CAP + pos] = bits;
      }
    }
  }
  __syncthreads();
  unsigned* __restrict__ gh = hist2 + (size_t)q*2048;
  for (int i = tid; i < 2048; i += 256) {
    const unsigned c = lh[i];
    if (c) atomicAdd(&gh[i], c);
  }
}

// Fused level-2 scan + level-3 histogram (from compact candidates, exact
// full-scan fallback on overflow) + level-3 scan -> final threshold bits.
__global__ __launch_bounds__(256) void sel23_all(
    const unsigned* __restrict__ hist2, const unsigned* __restrict__ prefix1,
    const unsigned* __restrict__ krem1, const unsigned* __restrict__ cnt,
    const unsigned* __restrict__ cand, const float* __restrict__ sims,
    unsigned* __restrict__ thb)
{
  const int q = blockIdx.x;
  const int t = threadIdx.x;
  __shared__ unsigned part[256];
  __shared__ unsigned lh[512];
  __shared__ unsigned sh_pfx2, sh_kr2;

  // ---- level-2 scan ----
  const unsigned* __restrict__ h2 = hist2 + (size_t)q*2048;
  unsigned sum = 0;
  #pragma unroll
  for (int i = 0; i < 8; ++i) sum += h2[t*8 + i];
  part[t] = sum;
  __syncthreads();
  if (t == 0) {
    const unsigned kr = krem1[q];
    unsigned cum = 0; int sc = 0;
    for (int c = 255; c >= 0; --c) {
      if (cum + part[c] >= kr) { sc = c; break; }
      cum += part[c];
    }
    unsigned cum2 = cum; int sb = sc*8;
    for (int b = sc*8 + 7; b >= sc*8; --b) {
      if (cum2 + h2[b] >= kr) { sb = b; break; }
      cum2 += h2[b];
    }
    sh_pfx2 = prefix1[q] | (((unsigned)sb) << 9);
    sh_kr2  = kr - cum2;
  }
  for (int i = t; i < 512; i += 256) lh[i] = 0;
  __syncthreads();

  // ---- level-3 histogram (bits[8:0]) ----
  const unsigned pfx2 = sh_pfx2;
  const unsigned n = cnt[q];
  if (n <= CAP) {
    const unsigned* __restrict__ cq = cand + (size_t)q*CAP;
    for (unsigned i = t; i < n; i += 256) {
      const unsigned b = cq[i];
      if ((b >> 9) == (pfx2 >> 9)) atomicAdd(&lh[b & 0x1ffu], 1u);
    }
  } else {  // overflow fallback: exact full re-scan of this sim plane
    const float* __restrict__ sq = sims + (size_t)q*NPIX;
    for (int i = t; i < NPIX; i += 256) {
      const unsigned b = __float_as_uint(sq[i]) & 0x7fffffffu;
      if ((b >> 9) == (pfx2 >> 9)) atomicAdd(&lh[b & 0x1ffu], 1u);
    }
  }
  __syncthreads();

  // ---- level-3 scan ----
  part[t] = lh[2*t] + lh[2*t + 1];
  __syncthreads();
  if (t == 0) {
    const unsigned kr = sh_kr2;
    unsigned cum = 0; int sc = 0;
    for (int c = 255; c >= 0; --c) {
      if (cum + part[c] >= kr) { sc = c; break; }
      cum += part[c];
    }
    unsigned cum2 = cum; int sb = 2*sc;
    for (int b = 2*sc + 1; b >= 2*sc; --b) {
      if (cum2 + lh[b] >= kr) { sb = b; break; }
      cum2 += lh[b];
    }
    thb[q] = pfx2 | (unsigned)sb;
  }
}

// Backward: per tile, stage thresholded sim_f (f=0..2) and accumulate all
// three fp32 convs in registers; single write of out.
__global__ __launch_bounds__(256) void bwd_all(
    const float* __restrict__ sims,
    const float* __restrict__ w3, const float* __restrict__ w5,
    const float* __restrict__ w7,
    const unsigned* __restrict__ thb, float* __restrict__ out)
{
  constexpr int P = 3, TW = TILE + 2*P, TWP = TW + 2;
  __shared__ float xt[TW][TWP];
  __shared__ float wsm[49];

  const int tid = threadIdx.x;
  const int s  = blockIdx.z;
  const int bx = blockIdx.x * TILE, by = blockIdx.y * TILE;
  const int tx  = tid & 63;
  const int ty0 = (tid >> 6) * 16;
  const float* const wp[NF] = {w3, w5, w7};

  float acc[16];
  #pragma unroll
  for (int r = 0; r < 16; ++r) acc[r] = 0.0f;

  #pragma unroll
  for (int f = 0; f < NF; ++f) {
    const int K = 3 + 2*f;
    __syncthreads();                       // xt reusable / wsm reusable
    if (tid < K*K) wsm[tid] = wp[f][tid];
    const unsigned th = thb[f*NSAMP + s];
    const float* __restrict__ ss = sims + ((size_t)f*NSAMP + s)*NPIX;
    for (int idx = tid; idx < TW*TW; idx += 256) {
      const int r = idx / TW, c = idx % TW;
      const int gy = by + r - P, gx = bx + c - P;
      float v = 0.0f;
      if (gy >= 0 && gy < HW && gx >= 0 && gx < HW) {
        v = ss[gy*HW + gx];
        const unsigned b = __float_as_uint(v) & 0x7fffffffu;
        if (b < th) v = 0.0f;
      }
      xt[r][c] = v;
    }
    __syncthreads();
    if (K == 3)      conv16_f32<3>(xt, wsm, tx, ty0, acc);
    else if (K == 5) conv16_f32<5>(xt, wsm, tx, ty0, acc);
    else             conv16_f32<7>(xt, wsm, tx, ty0, acc);
  }

  float* __restrict__ oo = out + (size_t)s*NPIX + (size_t)by*HW + bx;
  #pragma unroll
  for (int r = 0; r < 16; ++r)
    oo[(size_t)(ty0 + r)*HW + tx] = acc[r];
}

// ===========================================================================
// FALLBACK PATH (round-2 pipeline, ~65 MB ws) — used only if ws is small.
// ===========================================================================
template<int K>
__global__ __launch_bounds__(256) void conv_fwd_hist(
    const float* __restrict__ x, const float* __restrict__ w,
    float* __restrict__ sim, unsigned* __restrict__ hist)
{
  constexpr int P = K/2, TW = TILE + 2*P, TWP = TW + 2;
  __shared__ float xt[TW][TWP];
  __shared__ double wsm[K*K];
  __shared__ unsigned lh[2048];
  const int tid = threadIdx.x;
  if (tid < K*K) wsm[tid] = (double)w[tid];
  for (int i = tid; i < 2048; i += 256) lh[i] = 0;
  const int s = blockIdx.z;
  const int bx = blockIdx.x*TILE, by = blockIdx.y*TILE;
  const float* __restrict__ xs = x + (size_t)s*NPIX;
  for (int idx = tid; idx < TW*TW; idx += 256) {
    const int r = idx / TW, c = idx % TW;
    const int gy = by + r - P, gx = bx + c - P;
    float v = 0.0f;
    if (gy >= 0 && gy < HW && gx >= 0 && gx < HW) v = xs[gy*HW + gx];
    xt[r][c] = v;
  }
  __syncthreads();
  const int tx = tid & 63, ty0 = (tid >> 6)*16;
  double acc[16];
  #pragma unroll
  for (int r = 0; r < 16; ++r) acc[r] = 0.0;
  #pragma unroll
  for (int j = 0; j < K; ++j) {
    double dcol[16 + K - 1];
    #pragma unroll
    for (int y = 0; y < 16 + K - 1; ++y) dcol[y] = (double)xt[ty0 + y][tx + j];
    #pragma unroll
    for (int i = 0; i < K; ++i) {
      const double wv = wsm[i*K + j];
      #pragma unroll
      for (int r = 0; r < 16; ++r) acc[r] = fma(dcol[r + i], wv, acc[r]);
    }
  }
  float* __restrict__ so = sim + (size_t)s*NPIX + (size_t)by*HW + bx;
  #pragma unroll
  for (int r = 0; r < 16; ++r) {
    const float sv = (float)acc[r];
    so[(size_t)(ty0 + r)*HW + tx] = sv;
    atomicAdd(&lh[(__float_as_uint(sv) & 0x7fffffffu) >> 20], 1u);
  }
  __syncthreads();
  unsigned* __restrict__ gh = hist + s*2048;
  for (int i = tid; i < 2048; i += 256) {
    const unsigned c = lh[i];
    if (c) atomicAdd(&gh[i], c);
  }
}

template<int LEVEL>
__global__ __launch_bounds__(256) void hist_refine(
    const float* __restrict__ sim, const unsigned* __restrict__ prefix,
    unsigned* __restrict__ hist)
{
  constexpr int BINS = (LEVEL == 2) ? 2048 : 512;
  __shared__ unsigned lh[BINS];
  const int tid = threadIdx.x;
  for (int i = tid; i < BINS; i += 256) lh[i] = 0;
  __syncthreads();
  const int s = blockIdx.y;
  const unsigned pfx = prefix[s];
  const float4* __restrict__ p =
      (const float4*)(sim + (size_t)s*NPIX) + (size_t)blockIdx.x*1024;
  #pragma unroll
  for (int k = 0; k < 4; ++k) {
    const float4 v = p[k*256 + tid];
    const float f4[4] = {v.x, v.y, v.z, v.w};
    #pragma unroll
    for (int e = 0; e < 4; ++e) {
      const unsigned bits = __float_as_uint(f4[e]) & 0x7fffffffu;
      if (LEVEL == 2) {
        if ((bits >> 20) == (pfx >> 20)) atomicAdd(&lh[(bits >> 9) & 0x7ffu], 1u);
      } else {
        if ((bits >> 9) == (pfx >> 9)) atomicAdd(&lh[bits & 0x1ffu], 1u);
      }
    }
  }
  __syncthreads();
  unsigned* __restrict__ gh = hist + s*2048;
  for (int i = tid; i < BINS; i += 256) {
    const unsigned c = lh[i];
    if (c) atomicAdd(&gh[i], c);
  }
}

template<int LEVEL>
__global__ __launch_bounds__(256) void scan_level(
    unsigned* __restrict__ hist, unsigned* __restrict__ prefix,
    unsigned* __restrict__ krem, unsigned* __restrict__ thbits)
{
  constexpr int BINS = (LEVEL == 3) ? 512 : 2048;
  constexpr int C = BINS / 256;
  constexpr int SHIFT = (LEVEL == 1) ? 20 : (LEVEL == 2) ? 9 : 0;
  const int s = blockIdx.x;
  const int t = threadIdx.x;
  unsigned* __restrict__ h = hist + s*2048;
  __shared__ unsigned part[256];
  unsigned sum = 0;
  #pragma unroll
  for (int i = 0; i < C; ++i) sum += h[t*C + i];
  part[t] = sum;
  __syncthreads();
  if (t == 0) {
    const unsigned kr = (LEVEL == 1) ? (unsigned)KSEL : krem[s];
    unsigned cum = 0; int sc = 0;
    for (int c = 255; c >= 0; --c) {
      if (cum + part[c] >= kr) { sc = c; break; }
      cum += part[c];
    }
    unsigned cum2 = cum; int sb = sc*C;
    for (int b = sc*C + C - 1; b >= sc*C; --b) {
      if (cum2 + h[b] >= kr) { sb = b; break; }
      cum2 += h[b];
    }
    if (LEVEL == 1)      { prefix[s] = ((unsigned)sb) << SHIFT; krem[s] = kr - cum2; }
    else if (LEVEL == 2) { prefix[s] |= ((unsigned)sb) << SHIFT; krem[s] = kr - cum2; }
    else                 { thbits[s] = prefix[s] | (unsigned)sb; }
  }
  __syncthreads();
  for (int i = t; i < 2048; i += 256) h[i] = 0;
}

template<int K, bool FIRST>
__global__ __launch_bounds__(256) void conv_bwd(
    const float* __restrict__ sim, const float* __restrict__ w,
    const unsigned* __restrict__ thbits, float* __restrict__ out)
{
  constexpr int P = K/2, TW = TILE + 2*P, TWP = TW + 2;
  __shared__ float xt[TW][TWP];
  __shared__ float wsm[K*K];
  const int tid = threadIdx.x;
  if (tid < K*K) wsm[tid] = w[tid];
  const int s = blockIdx.z;
  const unsigned th = thbits[s];
  const int bx = blockIdx.x*TILE, by = blockIdx.y*TILE;
  const float* __restrict__ ss = sim + (size_t)s*NPIX;
  for (int idx = tid; idx < TW*TW; idx += 256) {
    const int r = idx / TW, c = idx % TW;
    const int gy = by + r - P, gx = bx + c - P;
    float v = 0.0f;
    if (gy >= 0 && gy < HW && gx >= 0 && gx < HW) {
      v = ss[gy*HW + gx];
      if ((__float_as_uint(v) & 0x7fffffffu) < th) v = 0.0f;
    }
    xt[r][c] = v;
  }
  __syncthreads();
  const int tx = tid & 63, ty0 = (tid >> 6)*16;
  float acc[16];
  #pragma unroll
  for (int r = 0; r < 16; ++r) acc[r] = 0.0f;
  #pragma unroll
  for (int j = 0; j < K; ++j) {
    float col[16 + K - 1];
    #pragma unroll
    for (int y = 0; y < 16 + K - 1; ++y) col[y] = xt[ty0 + y][tx + j];
    #pragma unroll
    for (int i = 0; i < K; ++i) {
      const float wv = wsm[i*K + j];
      #pragma unroll
      for (int r = 0; r < 16; ++r) acc[r] = fmaf(col[r + i], wv, acc[r]);
    }
  }
  float* __restrict__ oo = out + (size_t)s*NPIX + (size_t)by*HW + bx;
  #pragma unroll
  for (int r = 0; r < 16; ++r) {
    const size_t o = (size_t)(ty0 + r)*HW + tx;
    oo[o] = FIRST ? acc[r] : oo[o] + acc[r];
  }
}

// ===========================================================================
extern "C" void kernel_launch(void* const* d_in, const int* in_sizes, int n_in,
                              void* d_out, int out_size, void* d_ws, size_t ws_size,
                              hipStream_t stream)
{
  const float* x  = (const float*)d_in[0];
  const float* w3 = (const float*)d_in[1];
  const float* w5 = (const float*)d_in[2];
  const float* w7 = (const float*)d_in[3];
  float* out = (float*)d_out;
  char* ws = (char*)d_ws;

  const size_t SIMS_B  = (size_t)NF*NSAMP*NPIX*sizeof(float);   // 192 MB
  const size_t HIST_B  = (size_t)NQ*2048*sizeof(unsigned);      // 1.5 MB
  const size_t CAND_B  = (size_t)NQ*CAP*sizeof(unsigned);       // 12.6 MB
  const size_t NEED = SIMS_B + 2*HIST_B + 8*NQ*sizeof(unsigned) + CAND_B;

  if (ws_size >= NEED) {
    // ---------------- fused path ----------------
    float*    sims    = (float*)ws;
    unsigned* hist1   = (unsigned*)(ws + SIMS_B);
    unsigned* hist2   = hist1 + (size_t)NQ*2048;
    unsigned* cnt     = hist2 + (size_t)NQ*2048;
    unsigned* prefix1 = cnt + NQ;
    unsigned* krem1   = prefix1 + NQ;
    unsigned* thb     = krem1 + NQ;
    unsigned* cand    = thb + NQ + NQ;  // (spare NQ gap)

    // zero hist1, hist2, cnt (contiguous)
    hipMemsetAsync(hist1, 0, 2*HIST_B + NQ*sizeof(unsigned), stream);

    dim3 cb(256, 1, 1), cg(HW/TILE, HW/TILE, NSAMP);
    fwd_all<<<cg, cb, 0, stream>>>(x, w3, w5, w7, sims, hist1);
    scan1_all<<<NQ, 256, 0, stream>>>(hist1, prefix1, krem1);
    dim3 rg(NPIX/4096, NQ, 1);
    refine2_all<<<rg, cb, 0, stream>>>(sims, prefix1, hist2, cnt, cand);
    sel23_all<<<NQ, 256, 0, stream>>>(hist2, prefix1, krem1, cnt, cand, sims, thb);
    bwd_all<<<cg, cb, 0, stream>>>(sims, w3, w5, w7, thb, out);
  } else {
    // ---------------- fallback (round-2) path ----------------
    float* sim = (float*)ws;
    unsigned* hist   = (unsigned*)(ws + (size_t)NSAMP*NPIX*sizeof(float));
    unsigned* prefix = hist + NSAMP*2048;
    unsigned* krem   = prefix + NSAMP;
    unsigned* thb    = krem + NSAMP;
    hipMemsetAsync(hist, 0, NSAMP*2048*sizeof(unsigned), stream);
    dim3 cb(256, 1, 1), cg(HW/TILE, HW/TILE, NSAMP);
    dim3 rg(NPIX/4096, NSAMP, 1);

    conv_fwd_hist<3><<<cg, cb, 0, stream>>>(x, w3, sim, hist);
    scan_level<1><<<NSAMP, 256, 0, stream>>>(hist, prefix, krem, thb);
    hist_refine<2><<<rg, cb, 0, stream>>>(sim, prefix, hist);
    scan_level<2><<<NSAMP, 256, 0, stream>>>(hist, prefix, krem, thb);
    hist_refine<3><<<rg, cb, 0, stream>>>(sim, prefix, hist);
    scan_level<3><<<NSAMP, 256, 0, stream>>>(hist, prefix, krem, thb);
    conv_bwd<3, true><<<cg, cb, 0, stream>>>(sim, w3, thb, out);

    conv_fwd_hist<5><<<cg, cb, 0, stream>>>(x, w5, sim, hist);
    scan_level<1><<<NSAMP, 256, 0, stream>>>(hist, prefix, krem, thb);
    hist_refine<2><<<rg, cb, 0, stream>>>(sim, prefix, hist);
    scan_level<2><<<NSAMP, 256, 0, stream>>>(hist, prefix, krem, thb);
    hist_refine<3><<<rg, cb, 0, stream>>>(sim, prefix, hist);
    scan_level<3><<<NSAMP, 256, 0, stream>>>(hist, prefix, krem, thb);
    conv_bwd<5, false><<<cg, cb, 0, stream>>>(sim, w5, thb, out);

    conv_fwd_hist<7><<<cg, cb, 0, stream>>>(x, w7, sim, hist);
    scan_level<1><<<NSAMP, 256, 0, stream>>>(hist, prefix, krem, thb);
    hist_refine<2><<<rg, cb, 0, stream>>>(sim, prefix, hist);
    scan_level<2><<<NSAMP, 256, 0, stream>>>(hist, prefix, krem, thb);
    hist_refine<3><<<rg, cb, 0, stream>>>(sim, prefix, hist);
    scan_level<3><<<NSAMP, 256, 0, stream>>>(hist, prefix, krem, thb);
    conv_bwd<7, false><<<cg, cb, 0, stream>>>(sim, w7, thb, out);
  }
}

// Round 4
// 660.595 us; speedup vs baseline: 3.5802x; 3.5802x over previous
//
#include <hip/hip_runtime.h>

#define HW 512
#define NPIX (HW*HW)
#define NSAMP 64
#define KSEL 2621
#define TILE 64
#define NF 3
#define NQ (NF*NSAMP)
#define CAP 16384
#define CPAD 32   // cnt padding (uints) -> 128B per counter, no false sharing

// ===========================================================================
// Conv helpers: 64x64 tile staged with halo 3 (max filter), 16 outputs per
// thread. OFF recenters smaller filters inside the halo-3 tile.
// ===========================================================================
template<int K>
__device__ __forceinline__ void conv16_f64(
    const float (*xt)[TILE + 8], const double* __restrict__ wsm,
    int tx, int ty0, double* __restrict__ acc)
{
  constexpr int OFF = 3 - K/2;
  #pragma unroll
  for (int j = 0; j < K; ++j) {
    double dcol[16 + K - 1];
    #pragma unroll
    for (int y = 0; y < 16 + K - 1; ++y)
      dcol[y] = (double)xt[ty0 + y + OFF][tx + j + OFF];
    #pragma unroll
    for (int i = 0; i < K; ++i) {
      const double wv = wsm[i*K + j];
      #pragma unroll
      for (int r = 0; r < 16; ++r)
        acc[r] = fma(dcol[r + i], wv, acc[r]);
    }
  }
}

template<int K>
__device__ __forceinline__ void conv16_f32(
    const float (*xt)[TILE + 8], const float* __restrict__ wsm,
    int tx, int ty0, float* __restrict__ acc)
{
  constexpr int OFF = 3 - K/2;
  #pragma unroll
  for (int j = 0; j < K; ++j) {
    float col[16 + K - 1];
    #pragma unroll
    for (int y = 0; y < 16 + K - 1; ++y)
      col[y] = xt[ty0 + y + OFF][tx + j + OFF];
    #pragma unroll
    for (int i = 0; i < K; ++i) {
      const float wv = wsm[i*K + j];
      #pragma unroll
      for (int r = 0; r < 16; ++r)
        acc[r] = fmaf(col[r + i], wv, acc[r]);
    }
  }
}

// ===========================================================================
// FUSED PATH
// ===========================================================================

// Forward: stage x tile once, compute sim3/sim5/sim7 (fp64, exact selection),
// level-1 hist (bits[30:20], 2048 bins) per filter. q = f*NSAMP + s.
__global__ __launch_bounds__(256) void fwd_all(
    const float* __restrict__ x,
    const float* __restrict__ w3, const float* __restrict__ w5,
    const float* __restrict__ w7,
    float* __restrict__ sims, unsigned* __restrict__ hist1)
{
  constexpr int P = 3, TW = TILE + 2*P, TWP = TW + 2;
  __shared__ float xt[TW][TWP];
  __shared__ double wsm[49];
  __shared__ unsigned lh[2048];

  const int tid = threadIdx.x;
  const int s  = blockIdx.z;
  const int bx = blockIdx.x * TILE, by = blockIdx.y * TILE;
  const float* __restrict__ xs = x + (size_t)s*NPIX;

  for (int idx = tid; idx < TW*TW; idx += 256) {
    const int r = idx / TW, c = idx % TW;
    const int gy = by + r - P, gx = bx + c - P;
    float v = 0.0f;
    if (gy >= 0 && gy < HW && gx >= 0 && gx < HW) v = xs[gy*HW + gx];
    xt[r][c] = v;
  }

  const int tx  = tid & 63;
  const int ty0 = (tid >> 6) * 16;
  const float* const wp[NF] = {w3, w5, w7};

  #pragma unroll
  for (int f = 0; f < NF; ++f) {
    const int K = 3 + 2*f;
    __syncthreads();                       // xt ready / prev merge complete
    if (tid < K*K) wsm[tid] = (double)wp[f][tid];
    for (int i = tid; i < 2048; i += 256) lh[i] = 0;
    __syncthreads();

    double acc[16];
    #pragma unroll
    for (int r = 0; r < 16; ++r) acc[r] = 0.0;
    if (K == 3)      conv16_f64<3>(xt, wsm, tx, ty0, acc);
    else if (K == 5) conv16_f64<5>(xt, wsm, tx, ty0, acc);
    else             conv16_f64<7>(xt, wsm, tx, ty0, acc);

    float* __restrict__ so =
        sims + ((size_t)f*NSAMP + s)*NPIX + (size_t)by*HW + bx;
    #pragma unroll
    for (int r = 0; r < 16; ++r) {
      const float sv = (float)acc[r];
      so[(size_t)(ty0 + r)*HW + tx] = sv;
      const unsigned bits = __float_as_uint(sv) & 0x7fffffffu;
      atomicAdd(&lh[bits >> 20], 1u);
    }
    __syncthreads();
    unsigned* __restrict__ gh = hist1 + ((size_t)f*NSAMP + s)*2048;
    for (int i = tid; i < 2048; i += 256) {
      const unsigned c = lh[i];
      if (c) atomicAdd(&gh[i], c);
    }
  }
}

// Level-1 scan: one block per q.
__global__ __launch_bounds__(256) void scan1_all(
    const unsigned* __restrict__ hist1, unsigned* __restrict__ prefix1,
    unsigned* __restrict__ krem1)
{
  const int q = blockIdx.x;
  const int t = threadIdx.x;
  const unsigned* __restrict__ h = hist1 + (size_t)q*2048;
  __shared__ unsigned part[256];
  unsigned sum = 0;
  #pragma unroll
  for (int i = 0; i < 8; ++i) sum += h[t*8 + i];
  part[t] = sum;
  __syncthreads();
  if (t == 0) {
    const unsigned kr = KSEL;
    unsigned cum = 0; int sc = 0;
    for (int c = 255; c >= 0; --c) {
      if (cum + part[c] >= kr) { sc = c; break; }
      cum += part[c];
    }
    unsigned cum2 = cum; int sb = sc*8;
    for (int b = sc*8 + 7; b >= sc*8; --b) {
      if (cum2 + h[b] >= kr) { sb = b; break; }
      cum2 += h[b];
    }
    prefix1[q] = ((unsigned)sb) << 20;
    krem1[q]   = kr - cum2;
  }
}

// Compaction: stream sims once, collect elements in the selected level-1 bin
// into cand[q] via block-local LDS aggregation + ONE padded global atomic per
// block (round-3 lesson: per-element same-line device atomics serialized
// cross-XCD -> 1.8 ms).
__global__ __launch_bounds__(256) void refine2_all(
    const float* __restrict__ sims, const unsigned* __restrict__ prefix1,
    unsigned* __restrict__ cntp, unsigned* __restrict__ cand)
{
  __shared__ unsigned sb[4096];
  __shared__ unsigned scnt, sbase;
  const int tid = threadIdx.x;
  const int q = blockIdx.y;
  if (tid == 0) scnt = 0;
  __syncthreads();

  const unsigned pb = prefix1[q] >> 20;
  const float4* __restrict__ p =
      (const float4*)(sims + (size_t)q*NPIX) + (size_t)blockIdx.x*1024;
  #pragma unroll
  for (int k = 0; k < 4; ++k) {
    const float4 v = p[k*256 + tid];
    const float f4[4] = {v.x, v.y, v.z, v.w};
    #pragma unroll
    for (int e = 0; e < 4; ++e) {
      const unsigned bits = __float_as_uint(f4[e]) & 0x7fffffffu;
      if ((bits >> 20) == pb) sb[atomicAdd(&scnt, 1u)] = bits;
    }
  }
  __syncthreads();
  const unsigned nb = scnt;
  if (tid == 0) sbase = nb ? atomicAdd(&cntp[(size_t)q*CPAD], nb) : 0u;
  __syncthreads();
  const unsigned base = sbase;
  for (unsigned i = tid; i < nb; i += 256) {
    const unsigned pos = base + i;
    if (pos < CAP) cand[(size_t)q*CAP + pos] = sb[i];
  }
}

// Levels 2+3 entirely from the compact candidate list (exact full-scan
// fallback if the level-1 bin overflowed CAP). One block per q.
__global__ __launch_bounds__(256) void sel23_all(
    const unsigned* __restrict__ prefix1, const unsigned* __restrict__ krem1,
    const unsigned* __restrict__ cntp, const unsigned* __restrict__ cand,
    const float* __restrict__ sims, unsigned* __restrict__ thb)
{
  const int q = blockIdx.x;
  const int t = threadIdx.x;
  __shared__ unsigned lh[2048];
  __shared__ unsigned part[256];
  __shared__ unsigned sh_pfx2, sh_kr2;

  for (int i = t; i < 2048; i += 256) lh[i] = 0;
  __syncthreads();

  const unsigned n    = cntp[(size_t)q*CPAD];
  const unsigned pfx1 = prefix1[q];
  const unsigned* __restrict__ cq = cand + (size_t)q*CAP;
  const float*    __restrict__ sq = sims + (size_t)q*NPIX;
  const bool ok = (n <= CAP);

  // ---- level-2 histogram (bits[19:9]) ----
  if (ok) {
    for (unsigned i = t; i < n; i += 256)
      atomicAdd(&lh[(cq[i] >> 9) & 0x7ffu], 1u);
  } else {
    for (int i = t; i < NPIX; i += 256) {
      const unsigned b = __float_as_uint(sq[i]) & 0x7fffffffu;
      if ((b >> 20) == (pfx1 >> 20)) atomicAdd(&lh[(b >> 9) & 0x7ffu], 1u);
    }
  }
  __syncthreads();

  // ---- level-2 scan ----
  unsigned sum = 0;
  #pragma unroll
  for (int i = 0; i < 8; ++i) sum += lh[t*8 + i];
  part[t] = sum;
  __syncthreads();
  if (t == 0) {
    const unsigned kr = krem1[q];
    unsigned cum = 0; int sc = 0;
    for (int c = 255; c >= 0; --c) {
      if (cum + part[c] >= kr) { sc = c; break; }
      cum += part[c];
    }
    unsigned cum2 = cum; int sb = sc*8;
    for (int b = sc*8 + 7; b >= sc*8; --b) {
      if (cum2 + lh[b] >= kr) { sb = b; break; }
      cum2 += lh[b];
    }
    sh_pfx2 = pfx1 | (((unsigned)sb) << 9);
    sh_kr2  = kr - cum2;
  }
  __syncthreads();
  const unsigned pfx2 = sh_pfx2;

  // ---- level-3 histogram (bits[8:0]) ----
  for (int i = t; i < 512; i += 256) lh[i] = 0;
  __syncthreads();
  if (ok) {
    for (unsigned i = t; i < n; i += 256) {
      const unsigned b = cq[i];
      if ((b >> 9) == (pfx2 >> 9)) atomicAdd(&lh[b & 0x1ffu], 1u);
    }
  } else {
    for (int i = t; i < NPIX; i += 256) {
      const unsigned b = __float_as_uint(sq[i]) & 0x7fffffffu;
      if ((b >> 9) == (pfx2 >> 9)) atomicAdd(&lh[b & 0x1ffu], 1u);
    }
  }
  __syncthreads();

  // ---- level-3 scan ----
  part[t] = lh[2*t] + lh[2*t + 1];
  __syncthreads();
  if (t == 0) {
    const unsigned kr = sh_kr2;
    unsigned cum = 0; int sc = 0;
    for (int c = 255; c >= 0; --c) {
      if (cum + part[c] >= kr) { sc = c; break; }
      cum += part[c];
    }
    unsigned cum2 = cum; int sb = 2*sc;
    for (int b = 2*sc + 1; b >= 2*sc; --b) {
      if (cum2 + lh[b] >= kr) { sb = b; break; }
      cum2 += lh[b];
    }
    thb[q] = pfx2 | (unsigned)sb;
  }
}

// Backward: per tile, stage thresholded sim_f (f=0..2), accumulate all three
// fp32 convs in registers, single write of out.
__global__ __launch_bounds__(256) void bwd_all(
    const float* __restrict__ sims,
    const float* __restrict__ w3, const float* __restrict__ w5,
    const float* __restrict__ w7,
    const unsigned* __restrict__ thb, float* __restrict__ out)
{
  constexpr int P = 3, TW = TILE + 2*P, TWP = TW + 2;
  __shared__ float xt[TW][TWP];
  __shared__ float wsm[49];

  const int tid = threadIdx.x;
  const int s  = blockIdx.z;
  const int bx = blockIdx.x * TILE, by = blockIdx.y * TILE;
  const int tx  = tid & 63;
  const int ty0 = (tid >> 6) * 16;
  const float* const wp[NF] = {w3, w5, w7};

  float acc[16];
  #pragma unroll
  for (int r = 0; r < 16; ++r) acc[r] = 0.0f;

  #pragma unroll
  for (int f = 0; f < NF; ++f) {
    const int K = 3 + 2*f;
    __syncthreads();
    if (tid < K*K) wsm[tid] = wp[f][tid];
    const unsigned th = thb[f*NSAMP + s];
    const float* __restrict__ ss = sims + ((size_t)f*NSAMP + s)*NPIX;
    for (int idx = tid; idx < TW*TW; idx += 256) {
      const int r = idx / TW, c = idx % TW;
      const int gy = by + r - P, gx = bx + c - P;
      float v = 0.0f;
      if (gy >= 0 && gy < HW && gx >= 0 && gx < HW) {
        v = ss[gy*HW + gx];
        const unsigned b = __float_as_uint(v) & 0x7fffffffu;
        if (b < th) v = 0.0f;
      }
      xt[r][c] = v;
    }
    __syncthreads();
    if (K == 3)      conv16_f32<3>(xt, wsm, tx, ty0, acc);
    else if (K == 5) conv16_f32<5>(xt, wsm, tx, ty0, acc);
    else             conv16_f32<7>(xt, wsm, tx, ty0, acc);
  }

  float* __restrict__ oo = out + (size_t)s*NPIX + (size_t)by*HW + bx;
  #pragma unroll
  for (int r = 0; r < 16; ++r)
    oo[(size_t)(ty0 + r)*HW + tx] = acc[r];
}

// ===========================================================================
// FALLBACK PATH (round-2 pipeline, ~65 MB ws) — used only if ws is small.
// ===========================================================================
template<int K>
__global__ __launch_bounds__(256) void conv_fwd_hist(
    const float* __restrict__ x, const float* __restrict__ w,
    float* __restrict__ sim, unsigned* __restrict__ hist)
{
  constexpr int P = K/2, TW = TILE + 2*P, TWP = TW + 2;
  __shared__ float xt[TW][TWP];
  __shared__ double wsm[K*K];
  __shared__ unsigned lh[2048];
  const int tid = threadIdx.x;
  if (tid < K*K) wsm[tid] = (double)w[tid];
  for (int i = tid; i < 2048; i += 256) lh[i] = 0;
  const int s = blockIdx.z;
  const int bx = blockIdx.x*TILE, by = blockIdx.y*TILE;
  const float* __restrict__ xs = x + (size_t)s*NPIX;
  for (int idx = tid; idx < TW*TW; idx += 256) {
    const int r = idx / TW, c = idx % TW;
    const int gy = by + r - P, gx = bx + c - P;
    float v = 0.0f;
    if (gy >= 0 && gy < HW && gx >= 0 && gx < HW) v = xs[gy*HW + gx];
    xt[r][c] = v;
  }
  __syncthreads();
  const int tx = tid & 63, ty0 = (tid >> 6)*16;
  double acc[16];
  #pragma unroll
  for (int r = 0; r < 16; ++r) acc[r] = 0.0;
  #pragma unroll
  for (int j = 0; j < K; ++j) {
    double dcol[16 + K - 1];
    #pragma unroll
    for (int y = 0; y < 16 + K - 1; ++y) dcol[y] = (double)xt[ty0 + y][tx + j];
    #pragma unroll
    for (int i = 0; i < K; ++i) {
      const double wv = wsm[i*K + j];
      #pragma unroll
      for (int r = 0; r < 16; ++r) acc[r] = fma(dcol[r + i], wv, acc[r]);
    }
  }
  float* __restrict__ so = sim + (size_t)s*NPIX + (size_t)by*HW + bx;
  #pragma unroll
  for (int r = 0; r < 16; ++r) {
    const float sv = (float)acc[r];
    so[(size_t)(ty0 + r)*HW + tx] = sv;
    atomicAdd(&lh[(__float_as_uint(sv) & 0x7fffffffu) >> 20], 1u);
  }
  __syncthreads();
  unsigned* __restrict__ gh = hist + s*2048;
  for (int i = tid; i < 2048; i += 256) {
    const unsigned c = lh[i];
    if (c) atomicAdd(&gh[i], c);
  }
}

template<int LEVEL>
__global__ __launch_bounds__(256) void hist_refine(
    const float* __restrict__ sim, const unsigned* __restrict__ prefix,
    unsigned* __restrict__ hist)
{
  constexpr int BINS = (LEVEL == 2) ? 2048 : 512;
  __shared__ unsigned lh[BINS];
  const int tid = threadIdx.x;
  for (int i = tid; i < BINS; i += 256) lh[i] = 0;
  __syncthreads();
  const int s = blockIdx.y;
  const unsigned pfx = prefix[s];
  const float4* __restrict__ p =
      (const float4*)(sim + (size_t)s*NPIX) + (size_t)blockIdx.x*1024;
  #pragma unroll
  for (int k = 0; k < 4; ++k) {
    const float4 v = p[k*256 + tid];
    const float f4[4] = {v.x, v.y, v.z, v.w};
    #pragma unroll
    for (int e = 0; e < 4; ++e) {
      const unsigned bits = __float_as_uint(f4[e]) & 0x7fffffffu;
      if (LEVEL == 2) {
        if ((bits >> 20) == (pfx >> 20)) atomicAdd(&lh[(bits >> 9) & 0x7ffu], 1u);
      } else {
        if ((bits >> 9) == (pfx >> 9)) atomicAdd(&lh[bits & 0x1ffu], 1u);
      }
    }
  }
  __syncthreads();
  unsigned* __restrict__ gh = hist + s*2048;
  for (int i = tid; i < BINS; i += 256) {
    const unsigned c = lh[i];
    if (c) atomicAdd(&gh[i], c);
  }
}

template<int LEVEL>
__global__ __launch_bounds__(256) void scan_level(
    unsigned* __restrict__ hist, unsigned* __restrict__ prefix,
    unsigned* __restrict__ krem, unsigned* __restrict__ thbits)
{
  constexpr int BINS = (LEVEL == 3) ? 512 : 2048;
  constexpr int C = BINS / 256;
  constexpr int SHIFT = (LEVEL == 1) ? 20 : (LEVEL == 2) ? 9 : 0;
  const int s = blockIdx.x;
  const int t = threadIdx.x;
  unsigned* __restrict__ h = hist + s*2048;
  __shared__ unsigned part[256];
  unsigned sum = 0;
  #pragma unroll
  for (int i = 0; i < C; ++i) sum += h[t*C + i];
  part[t] = sum;
  __syncthreads();
  if (t == 0) {
    const unsigned kr = (LEVEL == 1) ? (unsigned)KSEL : krem[s];
    unsigned cum = 0; int sc = 0;
    for (int c = 255; c >= 0; --c) {
      if (cum + part[c] >= kr) { sc = c; break; }
      cum += part[c];
    }
    unsigned cum2 = cum; int sb = sc*C;
    for (int b = sc*C + C - 1; b >= sc*C; --b) {
      if (cum2 + h[b] >= kr) { sb = b; break; }
      cum2 += h[b];
    }
    if (LEVEL == 1)      { prefix[s] = ((unsigned)sb) << SHIFT; krem[s] = kr - cum2; }
    else if (LEVEL == 2) { prefix[s] |= ((unsigned)sb) << SHIFT; krem[s] = kr - cum2; }
    else                 { thbits[s] = prefix[s] | (unsigned)sb; }
  }
  __syncthreads();
  for (int i = t; i < 2048; i += 256) h[i] = 0;
}

template<int K, bool FIRST>
__global__ __launch_bounds__(256) void conv_bwd(
    const float* __restrict__ sim, const float* __restrict__ w,
    const unsigned* __restrict__ thbits, float* __restrict__ out)
{
  constexpr int P = K/2, TW = TILE + 2*P, TWP = TW + 2;
  __shared__ float xt[TW][TWP];
  __shared__ float wsm[K*K];
  const int tid = threadIdx.x;
  if (tid < K*K) wsm[tid] = w[tid];
  const int s = blockIdx.z;
  const unsigned th = thbits[s];
  const int bx = blockIdx.x*TILE, by = blockIdx.y*TILE;
  const float* __restrict__ ss = sim + (size_t)s*NPIX;
  for (int idx = tid; idx < TW*TW; idx += 256) {
    const int r = idx / TW, c = idx % TW;
    const int gy = by + r - P, gx = bx + c - P;
    float v = 0.0f;
    if (gy >= 0 && gy < HW && gx >= 0 && gx < HW) {
      v = ss[gy*HW + gx];
      if ((__float_as_uint(v) & 0x7fffffffu) < th) v = 0.0f;
    }
    xt[r][c] = v;
  }
  __syncthreads();
  const int tx = tid & 63, ty0 = (tid >> 6)*16;
  float acc[16];
  #pragma unroll
  for (int r = 0; r < 16; ++r) acc[r] = 0.0f;
  #pragma unroll
  for (int j = 0; j < K; ++j) {
    float col[16 + K - 1];
    #pragma unroll
    for (int y = 0; y < 16 + K - 1; ++y) col[y] = xt[ty0 + y][tx + j];
    #pragma unroll
    for (int i = 0; i < K; ++i) {
      const float wv = wsm[i*K + j];
      #pragma unroll
      for (int r = 0; r < 16; ++r) acc[r] = fmaf(col[r + i], wv, acc[r]);
    }
  }
  float* __restrict__ oo = out + (size_t)s*NPIX + (size_t)by*HW + bx;
  #pragma unroll
  for (int r = 0; r < 16; ++r) {
    const size_t o = (size_t)(ty0 + r)*HW + tx;
    oo[o] = FIRST ? acc[r] : oo[o] + acc[r];
  }
}

// ===========================================================================
extern "C" void kernel_launch(void* const* d_in, const int* in_sizes, int n_in,
                              void* d_out, int out_size, void* d_ws, size_t ws_size,
                              hipStream_t stream)
{
  const float* x  = (const float*)d_in[0];
  const float* w3 = (const float*)d_in[1];
  const float* w5 = (const float*)d_in[2];
  const float* w7 = (const float*)d_in[3];
  float* out = (float*)d_out;
  char* ws = (char*)d_ws;

  const size_t SIMS_B = (size_t)NF*NSAMP*NPIX*sizeof(float);   // 192 MB
  const size_t H1_B   = (size_t)NQ*2048*sizeof(unsigned);      // 1.5 MB
  const size_t CNT_B  = (size_t)NQ*CPAD*sizeof(unsigned);      // 24 KB
  const size_t CAND_B = (size_t)NQ*CAP*sizeof(unsigned);       // 12.6 MB
  const size_t NEED = SIMS_B + H1_B + CNT_B + 4*NQ*sizeof(unsigned) + CAND_B;

  if (ws_size >= NEED) {
    // ---------------- fused path ----------------
    float*    sims    = (float*)ws;
    unsigned* hist1   = (unsigned*)(ws + SIMS_B);
    unsigned* cntp    = hist1 + (size_t)NQ*2048;
    unsigned* prefix1 = cntp + (size_t)NQ*CPAD;
    unsigned* krem1   = prefix1 + NQ;
    unsigned* thb     = krem1 + NQ;
    unsigned* cand    = thb + NQ + NQ;   // spare NQ gap

    // zero hist1 + cntp (contiguous)
    hipMemsetAsync(hist1, 0, H1_B + CNT_B, stream);

    dim3 cb(256, 1, 1), cg(HW/TILE, HW/TILE, NSAMP);
    fwd_all<<<cg, cb, 0, stream>>>(x, w3, w5, w7, sims, hist1);
    scan1_all<<<NQ, 256, 0, stream>>>(hist1, prefix1, krem1);
    dim3 rg(NPIX/4096, NQ, 1);
    refine2_all<<<rg, cb, 0, stream>>>(sims, prefix1, cntp, cand);
    sel23_all<<<NQ, 256, 0, stream>>>(prefix1, krem1, cntp, cand, sims, thb);
    bwd_all<<<cg, cb, 0, stream>>>(sims, w3, w5, w7, thb, out);
  } else {
    // ---------------- fallback (round-2) path ----------------
    float* sim = (float*)ws;
    unsigned* hist   = (unsigned*)(ws + (size_t)NSAMP*NPIX*sizeof(float));
    unsigned* prefix = hist + NSAMP*2048;
    unsigned* krem   = prefix + NSAMP;
    unsigned* thb    = krem + NSAMP;
    hipMemsetAsync(hist, 0, NSAMP*2048*sizeof(unsigned), stream);
    dim3 cb(256, 1, 1), cg(HW/TILE, HW/TILE, NSAMP);
    dim3 rg(NPIX/4096, NSAMP, 1);

    conv_fwd_hist<3><<<cg, cb, 0, stream>>>(x, w3, sim, hist);
    scan_level<1><<<NSAMP, 256, 0, stream>>>(hist, prefix, krem, thb);
    hist_refine<2><<<rg, cb, 0, stream>>>(sim, prefix, hist);
    scan_level<2><<<NSAMP, 256, 0, stream>>>(hist, prefix, krem, thb);
    hist_refine<3><<<rg, cb, 0, stream>>>(sim, prefix, hist);
    scan_level<3><<<NSAMP, 256, 0, stream>>>(hist, prefix, krem, thb);
    conv_bwd<3, true><<<cg, cb, 0, stream>>>(sim, w3, thb, out);

    conv_fwd_hist<5><<<cg, cb, 0, stream>>>(x, w5, sim, hist);
    scan_level<1><<<NSAMP, 256, 0, stream>>>(hist, prefix, krem, thb);
    hist_refine<2><<<rg, cb, 0, stream>>>(sim, prefix, hist);
    scan_level<2><<<NSAMP, 256, 0, stream>>>(hist, prefix, krem, thb);
    hist_refine<3><<<rg, cb, 0, stream>>>(sim, prefix, hist);
    scan_level<3><<<NSAMP, 256, 0, stream>>>(hist, prefix, krem, thb);
    conv_bwd<5, false><<<cg, cb, 0, stream>>>(sim, w5, thb, out);

    conv_fwd_hist<7><<<cg, cb, 0, stream>>>(x, w7, sim, hist);
    scan_level<1><<<NSAMP, 256, 0, stream>>>(hist, prefix, krem, thb);
    hist_refine<2><<<rg, cb, 0, stream>>>(sim, prefix, hist);
    scan_level<2><<<NSAMP, 256, 0, stream>>>(hist, prefix, krem, thb);
    hist_refine<3><<<rg, cb, 0, stream>>>(sim, prefix, hist);
    scan_level<3><<<NSAMP, 256, 0, stream>>>(hist, prefix, krem, thb);
    conv_bwd<7, false><<<cg, cb, 0, stream>>>(sim, w7, thb, out);
  }
}

// Round 5
// 472.625 us; speedup vs baseline: 5.0040x; 1.3977x over previous
//
#include <hip/hip_runtime.h>

#define HW 512
#define NPIX (HW*HW)
#define NSAMP 64
#define KSEL 2621
#define NF 3
#define NQ (NF*NSAMP)
#define CAP 16384
#define CPAD 32     // cnt padding (uints) -> 128B per counter, no false sharing

#define ROWS 16     // output rows per strip
#define HALO 3      // max filter halo
#define TR (ROWS + 2*HALO)   // 22 staged rows
#define LSTR 520    // LDS row stride in floats (16B-aligned, bank-friendly)

// ===========================================================================
// FUSED PATH — full-width 512x16 row strips, 512 threads, 1 col x 16 rows
// per thread. Staging is coalesced float4 with pow2 index math (round-4
// lesson: 3x scalar staging phases with /70 %70 math left bwd latency-bound
// at 430us, 18% VALU, 7% HBM).
// ===========================================================================

// Forward: stage x strip once, compute sim3/sim5/sim7 (fp64 -> exact
// selection), level-1 hist (bits[30:20], 2048 bins) per filter.
__global__ __launch_bounds__(512, 4) void fwd_all(
    const float* __restrict__ x,
    const float* __restrict__ w3, const float* __restrict__ w5,
    const float* __restrict__ w7,
    float* __restrict__ sims, unsigned* __restrict__ hist1)
{
  __shared__ float xt[TR][LSTR];
  __shared__ double wsm[49];
  __shared__ unsigned lh[2048];

  const int tid = threadIdx.x;
  const int s  = blockIdx.y;
  const int by = blockIdx.x * ROWS;
  const float* __restrict__ xs = x + (size_t)s*NPIX;

  // zero x-halo pads: cols 0..3 and 516..519, all TR rows
  if (tid < TR*8) {
    const int r = tid >> 3, c = tid & 7;
    xt[r][(c < 4) ? c : 512 + c] = 0.0f;
  }
  // stage TR rows x 128 float4 (data at float offset 4 -> 16B aligned)
  for (int idx = tid; idx < TR*128; idx += 512) {
    const int r = idx >> 7, c4 = idx & 127;
    const int gy = by + r - HALO;
    float4 v = make_float4(0.f, 0.f, 0.f, 0.f);
    if (gy >= 0 && gy < HW)
      v = ((const float4*)(xs + (size_t)gy*HW))[c4];
    *(float4*)&xt[r][4 + 4*c4] = v;
  }

  const int tx = tid;  // output column 0..511
  const float* const wp[NF] = {w3, w5, w7};

  #pragma unroll
  for (int f = 0; f < NF; ++f) {
    const int K = 3 + 2*f;
    __syncthreads();                    // staging done / prev merge done
    if (tid < K*K) wsm[tid] = (double)wp[f][tid];
    for (int i = tid; i < 2048; i += 512) lh[i] = 0;
    __syncthreads();

    double acc[ROWS];
    #pragma unroll
    for (int r = 0; r < ROWS; ++r) acc[r] = 0.0;

    // row offset: ROFF = HALO - K/2 ; col offset: COFF = 4 - K/2
    if (K == 3) {
      #pragma unroll
      for (int j = 0; j < 3; ++j) {
        double dcol[ROWS + 2];
        #pragma unroll
        for (int y = 0; y < ROWS + 2; ++y) dcol[y] = (double)xt[y + 2][tx + j + 3];
        #pragma unroll
        for (int i = 0; i < 3; ++i) {
          const double wv = wsm[i*3 + j];
          #pragma unroll
          for (int r = 0; r < ROWS; ++r) acc[r] = fma(dcol[r + i], wv, acc[r]);
        }
      }
    } else if (K == 5) {
      #pragma unroll
      for (int j = 0; j < 5; ++j) {
        double dcol[ROWS + 4];
        #pragma unroll
        for (int y = 0; y < ROWS + 4; ++y) dcol[y] = (double)xt[y + 1][tx + j + 2];
        #pragma unroll
        for (int i = 0; i < 5; ++i) {
          const double wv = wsm[i*5 + j];
          #pragma unroll
          for (int r = 0; r < ROWS; ++r) acc[r] = fma(dcol[r + i], wv, acc[r]);
        }
      }
    } else {
      #pragma unroll
      for (int j = 0; j < 7; ++j) {
        double dcol[ROWS + 6];
        #pragma unroll
        for (int y = 0; y < ROWS + 6; ++y) dcol[y] = (double)xt[y][tx + j + 1];
        #pragma unroll
        for (int i = 0; i < 7; ++i) {
          const double wv = wsm[i*7 + j];
          #pragma unroll
          for (int r = 0; r < ROWS; ++r) acc[r] = fma(dcol[r + i], wv, acc[r]);
        }
      }
    }

    float* __restrict__ so =
        sims + ((size_t)f*NSAMP + s)*NPIX + (size_t)by*HW + tx;
    #pragma unroll
    for (int r = 0; r < ROWS; ++r) {
      const float sv = (float)acc[r];
      so[(size_t)r*HW] = sv;
      atomicAdd(&lh[(__float_as_uint(sv) & 0x7fffffffu) >> 20], 1u);
    }
    __syncthreads();
    unsigned* __restrict__ gh = hist1 + ((size_t)f*NSAMP + s)*2048;
    for (int i = tid; i < 2048; i += 512) {
      const unsigned c = lh[i];
      if (c) atomicAdd(&gh[i], c);
    }
  }
}

// Level-1 scan: one block per q.
__global__ __launch_bounds__(256) void scan1_all(
    const unsigned* __restrict__ hist1, unsigned* __restrict__ prefix1,
    unsigned* __restrict__ krem1)
{
  const int q = blockIdx.x;
  const int t = threadIdx.x;
  const unsigned* __restrict__ h = hist1 + (size_t)q*2048;
  __shared__ unsigned part[256];
  unsigned sum = 0;
  #pragma unroll
  for (int i = 0; i < 8; ++i) sum += h[t*8 + i];
  part[t] = sum;
  __syncthreads();
  if (t == 0) {
    const unsigned kr = KSEL;
    unsigned cum = 0; int sc = 0;
    for (int c = 255; c >= 0; --c) {
      if (cum + part[c] >= kr) { sc = c; break; }
      cum += part[c];
    }
    unsigned cum2 = cum; int sb = sc*8;
    for (int b = sc*8 + 7; b >= sc*8; --b) {
      if (cum2 + h[b] >= kr) { sb = b; break; }
      cum2 += h[b];
    }
    prefix1[q] = ((unsigned)sb) << 20;
    krem1[q]   = kr - cum2;
  }
}

// Compaction: block-local LDS aggregation + ONE padded global atomic per
// block (round-3 lesson: per-element same-line device atomics -> 1.8 ms).
__global__ __launch_bounds__(256) void refine2_all(
    const float* __restrict__ sims, const unsigned* __restrict__ prefix1,
    unsigned* __restrict__ cntp, unsigned* __restrict__ cand)
{
  __shared__ unsigned sb[4096];
  __shared__ unsigned scnt, sbase;
  const int tid = threadIdx.x;
  const int q = blockIdx.y;
  if (tid == 0) scnt = 0;
  __syncthreads();

  const unsigned pb = prefix1[q] >> 20;
  const float4* __restrict__ p =
      (const float4*)(sims + (size_t)q*NPIX) + (size_t)blockIdx.x*1024;
  #pragma unroll
  for (int k = 0; k < 4; ++k) {
    const float4 v = p[k*256 + tid];
    const float f4[4] = {v.x, v.y, v.z, v.w};
    #pragma unroll
    for (int e = 0; e < 4; ++e) {
      const unsigned bits = __float_as_uint(f4[e]) & 0x7fffffffu;
      if ((bits >> 20) == pb) sb[atomicAdd(&scnt, 1u)] = bits;
    }
  }
  __syncthreads();
  const unsigned nb = scnt;
  if (tid == 0) sbase = nb ? atomicAdd(&cntp[(size_t)q*CPAD], nb) : 0u;
  __syncthreads();
  const unsigned base = sbase;
  for (unsigned i = tid; i < nb; i += 256) {
    const unsigned pos = base + i;
    if (pos < CAP) cand[(size_t)q*CAP + pos] = sb[i];
  }
}

// Levels 2+3 from the compact candidate list (exact full-scan fallback if
// the level-1 bin overflowed CAP). One block per q.
__global__ __launch_bounds__(256) void sel23_all(
    const unsigned* __restrict__ prefix1, const unsigned* __restrict__ krem1,
    const unsigned* __restrict__ cntp, const unsigned* __restrict__ cand,
    const float* __restrict__ sims, unsigned* __restrict__ thb)
{
  const int q = blockIdx.x;
  const int t = threadIdx.x;
  __shared__ unsigned lh[2048];
  __shared__ unsigned part[256];
  __shared__ unsigned sh_pfx2, sh_kr2;

  for (int i = t; i < 2048; i += 256) lh[i] = 0;
  __syncthreads();

  const unsigned n    = cntp[(size_t)q*CPAD];
  const unsigned pfx1 = prefix1[q];
  const unsigned* __restrict__ cq = cand + (size_t)q*CAP;
  const float*    __restrict__ sq = sims + (size_t)q*NPIX;
  const bool ok = (n <= CAP);

  if (ok) {
    for (unsigned i = t; i < n; i += 256)
      atomicAdd(&lh[(cq[i] >> 9) & 0x7ffu], 1u);
  } else {
    for (int i = t; i < NPIX; i += 256) {
      const unsigned b = __float_as_uint(sq[i]) & 0x7fffffffu;
      if ((b >> 20) == (pfx1 >> 20)) atomicAdd(&lh[(b >> 9) & 0x7ffu], 1u);
    }
  }
  __syncthreads();

  unsigned sum = 0;
  #pragma unroll
  for (int i = 0; i < 8; ++i) sum += lh[t*8 + i];
  part[t] = sum;
  __syncthreads();
  if (t == 0) {
    const unsigned kr = krem1[q];
    unsigned cum = 0; int sc = 0;
    for (int c = 255; c >= 0; --c) {
      if (cum + part[c] >= kr) { sc = c; break; }
      cum += part[c];
    }
    unsigned cum2 = cum; int sb = sc*8;
    for (int b = sc*8 + 7; b >= sc*8; --b) {
      if (cum2 + lh[b] >= kr) { sb = b; break; }
      cum2 += lh[b];
    }
    sh_pfx2 = pfx1 | (((unsigned)sb) << 9);
    sh_kr2  = kr - cum2;
  }
  __syncthreads();
  const unsigned pfx2 = sh_pfx2;

  for (int i = t; i < 512; i += 256) lh[i] = 0;
  __syncthreads();
  if (ok) {
    for (unsigned i = t; i < n; i += 256) {
      const unsigned b = cq[i];
      if ((b >> 9) == (pfx2 >> 9)) atomicAdd(&lh[b & 0x1ffu], 1u);
    }
  } else {
    for (int i = t; i < NPIX; i += 256) {
      const unsigned b = __float_as_uint(sq[i]) & 0x7fffffffu;
      if ((b >> 9) == (pfx2 >> 9)) atomicAdd(&lh[b & 0x1ffu], 1u);
    }
  }
  __syncthreads();

  part[t] = lh[2*t] + lh[2*t + 1];
  __syncthreads();
  if (t == 0) {
    const unsigned kr = sh_kr2;
    unsigned cum = 0; int sc = 0;
    for (int c = 255; c >= 0; --c) {
      if (cum + part[c] >= kr) { sc = c; break; }
      cum += part[c];
    }
    unsigned cum2 = cum; int sb = 2*sc;
    for (int b = 2*sc + 1; b >= 2*sc; --b) {
      if (cum2 + lh[b] >= kr) { sb = b; break; }
      cum2 += lh[b];
    }
    thb[q] = pfx2 | (unsigned)sb;
  }
}

// Backward: per strip, for each filter stage thresholded sim_f (coalesced
// float4, threshold applied per component), conv fp32, accumulate in regs,
// single write of out.
__global__ __launch_bounds__(512, 4) void bwd_all(
    const float* __restrict__ sims,
    const float* __restrict__ w3, const float* __restrict__ w5,
    const float* __restrict__ w7,
    const unsigned* __restrict__ thb, float* __restrict__ out)
{
  __shared__ float xt[TR][LSTR];
  __shared__ float wsm[49];

  const int tid = threadIdx.x;
  const int s  = blockIdx.y;
  const int by = blockIdx.x * ROWS;
  const int tx = tid;
  const float* const wp[NF] = {w3, w5, w7};

  // zero x-halo pads once (never overwritten by staging)
  if (tid < TR*8) {
    const int r = tid >> 3, c = tid & 7;
    xt[r][(c < 4) ? c : 512 + c] = 0.0f;
  }

  float acc[ROWS];
  #pragma unroll
  for (int r = 0; r < ROWS; ++r) acc[r] = 0.0f;

  #pragma unroll
  for (int f = 0; f < NF; ++f) {
    const int K = 3 + 2*f;
    __syncthreads();                    // pads done / prev conv done
    if (tid < K*K) wsm[tid] = wp[f][tid];
    const unsigned th = thb[f*NSAMP + s];
    const float* __restrict__ ss = sims + ((size_t)f*NSAMP + s)*NPIX;

    for (int idx = tid; idx < TR*128; idx += 512) {
      const int r = idx >> 7, c4 = idx & 127;
      const int gy = by + r - HALO;
      float4 v = make_float4(0.f, 0.f, 0.f, 0.f);
      if (gy >= 0 && gy < HW) {
        v = ((const float4*)(ss + (size_t)gy*HW))[c4];
        if ((__float_as_uint(v.x) & 0x7fffffffu) < th) v.x = 0.0f;
        if ((__float_as_uint(v.y) & 0x7fffffffu) < th) v.y = 0.0f;
        if ((__float_as_uint(v.z) & 0x7fffffffu) < th) v.z = 0.0f;
        if ((__float_as_uint(v.w) & 0x7fffffffu) < th) v.w = 0.0f;
      }
      *(float4*)&xt[r][4 + 4*c4] = v;
    }
    __syncthreads();

    if (K == 3) {
      #pragma unroll
      for (int j = 0; j < 3; ++j) {
        float col[ROWS + 2];
        #pragma unroll
        for (int y = 0; y < ROWS + 2; ++y) col[y] = xt[y + 2][tx + j + 3];
        #pragma unroll
        for (int i = 0; i < 3; ++i) {
          const float wv = wsm[i*3 + j];
          #pragma unroll
          for (int r = 0; r < ROWS; ++r) acc[r] = fmaf(col[r + i], wv, acc[r]);
        }
      }
    } else if (K == 5) {
      #pragma unroll
      for (int j = 0; j < 5; ++j) {
        float col[ROWS + 4];
        #pragma unroll
        for (int y = 0; y < ROWS + 4; ++y) col[y] = xt[y + 1][tx + j + 2];
        #pragma unroll
        for (int i = 0; i < 5; ++i) {
          const float wv = wsm[i*5 + j];
          #pragma unroll
          for (int r = 0; r < ROWS; ++r) acc[r] = fmaf(col[r + i], wv, acc[r]);
        }
      }
    } else {
      #pragma unroll
      for (int j = 0; j < 7; ++j) {
        float col[ROWS + 6];
        #pragma unroll
        for (int y = 0; y < ROWS + 6; ++y) col[y] = xt[y][tx + j + 1];
        #pragma unroll
        for (int i = 0; i < 7; ++i) {
          const float wv = wsm[i*7 + j];
          #pragma unroll
          for (int r = 0; r < ROWS; ++r) acc[r] = fmaf(col[r + i], wv, acc[r]);
        }
      }
    }
  }

  float* __restrict__ oo = out + (size_t)s*NPIX + (size_t)by*HW + tx;
  #pragma unroll
  for (int r = 0; r < ROWS; ++r)
    oo[(size_t)r*HW] = acc[r];
}

// ===========================================================================
extern "C" void kernel_launch(void* const* d_in, const int* in_sizes, int n_in,
                              void* d_out, int out_size, void* d_ws, size_t ws_size,
                              hipStream_t stream)
{
  const float* x  = (const float*)d_in[0];
  const float* w3 = (const float*)d_in[1];
  const float* w5 = (const float*)d_in[2];
  const float* w7 = (const float*)d_in[3];
  float* out = (float*)d_out;
  char* ws = (char*)d_ws;

  const size_t SIMS_B = (size_t)NF*NSAMP*NPIX*sizeof(float);   // 192 MB
  const size_t H1_B   = (size_t)NQ*2048*sizeof(unsigned);      // 1.5 MB
  const size_t CNT_B  = (size_t)NQ*CPAD*sizeof(unsigned);      // 24 KB

  float*    sims    = (float*)ws;
  unsigned* hist1   = (unsigned*)(ws + SIMS_B);
  unsigned* cntp    = hist1 + (size_t)NQ*2048;
  unsigned* prefix1 = cntp + (size_t)NQ*CPAD;
  unsigned* krem1   = prefix1 + NQ;
  unsigned* thb     = krem1 + NQ;
  unsigned* cand    = thb + NQ + NQ;   // spare NQ gap

  // zero hist1 + cntp (contiguous)
  hipMemsetAsync(hist1, 0, H1_B + CNT_B, stream);

  dim3 sb512(512, 1, 1), sg(HW/ROWS, NSAMP, 1);
  fwd_all<<<sg, sb512, 0, stream>>>(x, w3, w5, w7, sims, hist1);
  scan1_all<<<NQ, 256, 0, stream>>>(hist1, prefix1, krem1);
  dim3 rg(NPIX/4096, NQ, 1);
  refine2_all<<<rg, dim3(256,1,1), 0, stream>>>(sims, prefix1, cntp, cand);
  sel23_all<<<NQ, 256, 0, stream>>>(prefix1, krem1, cntp, cand, sims, thb);
  bwd_all<<<sg, sb512, 0, stream>>>(sims, w3, w5, w7, thb, out);
}

// Round 6
// 331.189 us; speedup vs baseline: 7.1410x; 1.4271x over previous
//
#include <hip/hip_runtime.h>

#define HW 512
#define NPIX (HW*HW)
#define NSAMP 64
#define KSEL 2621
#define NF 3
#define NQ (NF*NSAMP)
#define CAP 16384
#define CPAD 32     // cnt padding (uints) -> 128B per counter, no false sharing

#define ROWS 16     // output rows per strip
#define HALO 3      // max filter halo
#define TR (ROWS + 2*HALO)   // 22 staged rows
#define LSTR 520    // LDS row stride in floats (16B-aligned, bank-friendly)

// ===========================================================================
// Row-streaming conv: for each staged row y, load a K-wide window once and
// scatter-accumulate into acc[y-i]. Live set = v[K] + acc[ROWS] (round-5
// lesson: col-window version kept 22-wide windows live -> regalloc at the
// launch_bounds(512,4)-forced 64-VGPR budget spilled ~550B/thread to scratch,
// 638MB phantom HBM writes).
// ===========================================================================
template<int K>
__device__ __forceinline__ void conv_rows_f64(
    const float (*xt)[LSTR], const double* __restrict__ wsm,
    int tx, double* __restrict__ acc)
{
  constexpr int ROFF = HALO - K/2;
  constexpr int COFF = 4 - K/2;
  #pragma unroll
  for (int y = 0; y < ROWS + K - 1; ++y) {
    double v[K];
    #pragma unroll
    for (int j = 0; j < K; ++j)
      v[j] = (double)xt[y + ROFF][tx + j + COFF];
    #pragma unroll
    for (int i = 0; i < K; ++i) {
      const int r = y - i;                 // compile-time after unroll
      if (r >= 0 && r < ROWS) {
        #pragma unroll
        for (int j = 0; j < K; ++j)
          acc[r] = fma(v[j], wsm[i*K + j], acc[r]);
      }
    }
  }
}

template<int K>
__device__ __forceinline__ void conv_rows_f32(
    const float (*xt)[LSTR], const float* __restrict__ wsm,
    int tx, float* __restrict__ acc)
{
  constexpr int ROFF = HALO - K/2;
  constexpr int COFF = 4 - K/2;
  #pragma unroll
  for (int y = 0; y < ROWS + K - 1; ++y) {
    float v[K];
    #pragma unroll
    for (int j = 0; j < K; ++j)
      v[j] = xt[y + ROFF][tx + j + COFF];
    #pragma unroll
    for (int i = 0; i < K; ++i) {
      const int r = y - i;
      if (r >= 0 && r < ROWS) {
        #pragma unroll
        for (int j = 0; j < K; ++j)
          acc[r] = fmaf(v[j], wsm[i*K + j], acc[r]);
      }
    }
  }
}

// ===========================================================================
// Forward: full-width 512x16 strip, stage x once (coalesced float4, pow2
// index math), compute sim3/sim5/sim7 in fp64 (exact selection vs numpy
// fp64 reference), level-1 hist (bits[30:20], 2048 bins) per filter.
// ===========================================================================
__global__ __launch_bounds__(512, 2) void fwd_all(
    const float* __restrict__ x,
    const float* __restrict__ w3, const float* __restrict__ w5,
    const float* __restrict__ w7,
    float* __restrict__ sims, unsigned* __restrict__ hist1)
{
  __shared__ float xt[TR][LSTR];
  __shared__ double wsm[49];
  __shared__ unsigned lh[2048];

  const int tid = threadIdx.x;
  const int s  = blockIdx.y;
  const int by = blockIdx.x * ROWS;
  const float* __restrict__ xs = x + (size_t)s*NPIX;

  // zero x-halo pads: cols 0..3 and 516..519, all TR rows
  if (tid < TR*8) {
    const int r = tid >> 3, c = tid & 7;
    xt[r][(c < 4) ? c : 512 + c] = 0.0f;
  }
  // stage TR rows x 128 float4 (data at float offset 4 -> 16B aligned)
  for (int idx = tid; idx < TR*128; idx += 512) {
    const int r = idx >> 7, c4 = idx & 127;
    const int gy = by + r - HALO;
    float4 v = make_float4(0.f, 0.f, 0.f, 0.f);
    if (gy >= 0 && gy < HW)
      v = ((const float4*)(xs + (size_t)gy*HW))[c4];
    *(float4*)&xt[r][4 + 4*c4] = v;
  }

  const int tx = tid;  // output column 0..511
  const float* const wp[NF] = {w3, w5, w7};

  #pragma unroll
  for (int f = 0; f < NF; ++f) {
    __syncthreads();                    // staging done / prev merge done
    if (tid < 49) wsm[tid] = (tid < (3+2*f)*(3+2*f)) ? (double)wp[f][tid] : 0.0;
    for (int i = tid; i < 2048; i += 512) lh[i] = 0;
    __syncthreads();

    double acc[ROWS];
    #pragma unroll
    for (int r = 0; r < ROWS; ++r) acc[r] = 0.0;
    if (f == 0)      conv_rows_f64<3>(xt, wsm, tx, acc);
    else if (f == 1) conv_rows_f64<5>(xt, wsm, tx, acc);
    else             conv_rows_f64<7>(xt, wsm, tx, acc);

    float* __restrict__ so =
        sims + ((size_t)f*NSAMP + s)*NPIX + (size_t)by*HW + tx;
    #pragma unroll
    for (int r = 0; r < ROWS; ++r) {
      const float sv = (float)acc[r];
      so[(size_t)r*HW] = sv;
      atomicAdd(&lh[(__float_as_uint(sv) & 0x7fffffffu) >> 20], 1u);
    }
    __syncthreads();
    unsigned* __restrict__ gh = hist1 + ((size_t)f*NSAMP + s)*2048;
    for (int i = tid; i < 2048; i += 512) {
      const unsigned c = lh[i];
      if (c) atomicAdd(&gh[i], c);
    }
  }
}

// Level-1 scan: one block per q.
__global__ __launch_bounds__(256) void scan1_all(
    const unsigned* __restrict__ hist1, unsigned* __restrict__ prefix1,
    unsigned* __restrict__ krem1)
{
  const int q = blockIdx.x;
  const int t = threadIdx.x;
  const unsigned* __restrict__ h = hist1 + (size_t)q*2048;
  __shared__ unsigned part[256];
  unsigned sum = 0;
  #pragma unroll
  for (int i = 0; i < 8; ++i) sum += h[t*8 + i];
  part[t] = sum;
  __syncthreads();
  if (t == 0) {
    const unsigned kr = KSEL;
    unsigned cum = 0; int sc = 0;
    for (int c = 255; c >= 0; --c) {
      if (cum + part[c] >= kr) { sc = c; break; }
      cum += part[c];
    }
    unsigned cum2 = cum; int sb = sc*8;
    for (int b = sc*8 + 7; b >= sc*8; --b) {
      if (cum2 + h[b] >= kr) { sb = b; break; }
      cum2 += h[b];
    }
    prefix1[q] = ((unsigned)sb) << 20;
    krem1[q]   = kr - cum2;
  }
}

// Compaction: block-local LDS aggregation + ONE padded global atomic per
// block (round-3 lesson: per-element same-line device atomics -> 1.8 ms).
__global__ __launch_bounds__(256) void refine2_all(
    const float* __restrict__ sims, const unsigned* __restrict__ prefix1,
    unsigned* __restrict__ cntp, unsigned* __restrict__ cand)
{
  __shared__ unsigned sb[4096];
  __shared__ unsigned scnt, sbase;
  const int tid = threadIdx.x;
  const int q = blockIdx.y;
  if (tid == 0) scnt = 0;
  __syncthreads();

  const unsigned pb = prefix1[q] >> 20;
  const float4* __restrict__ p =
      (const float4*)(sims + (size_t)q*NPIX) + (size_t)blockIdx.x*1024;
  #pragma unroll
  for (int k = 0; k < 4; ++k) {
    const float4 v = p[k*256 + tid];
    const float f4[4] = {v.x, v.y, v.z, v.w};
    #pragma unroll
    for (int e = 0; e < 4; ++e) {
      const unsigned bits = __float_as_uint(f4[e]) & 0x7fffffffu;
      if ((bits >> 20) == pb) sb[atomicAdd(&scnt, 1u)] = bits;
    }
  }
  __syncthreads();
  const unsigned nb = scnt;
  if (tid == 0) sbase = nb ? atomicAdd(&cntp[(size_t)q*CPAD], nb) : 0u;
  __syncthreads();
  const unsigned base = sbase;
  for (unsigned i = tid; i < nb; i += 256) {
    const unsigned pos = base + i;
    if (pos < CAP) cand[(size_t)q*CAP + pos] = sb[i];
  }
}

// Levels 2+3 from the compact candidate list (exact full-scan fallback if
// the level-1 bin overflowed CAP). One block per q.
__global__ __launch_bounds__(256) void sel23_all(
    const unsigned* __restrict__ prefix1, const unsigned* __restrict__ krem1,
    const unsigned* __restrict__ cntp, const unsigned* __restrict__ cand,
    const float* __restrict__ sims, unsigned* __restrict__ thb)
{
  const int q = blockIdx.x;
  const int t = threadIdx.x;
  __shared__ unsigned lh[2048];
  __shared__ unsigned part[256];
  __shared__ unsigned sh_pfx2, sh_kr2;

  for (int i = t; i < 2048; i += 256) lh[i] = 0;
  __syncthreads();

  const unsigned n    = cntp[(size_t)q*CPAD];
  const unsigned pfx1 = prefix1[q];
  const unsigned* __restrict__ cq = cand + (size_t)q*CAP;
  const float*    __restrict__ sq = sims + (size_t)q*NPIX;
  const bool ok = (n <= CAP);

  if (ok) {
    for (unsigned i = t; i < n; i += 256)
      atomicAdd(&lh[(cq[i] >> 9) & 0x7ffu], 1u);
  } else {
    for (int i = t; i < NPIX; i += 256) {
      const unsigned b = __float_as_uint(sq[i]) & 0x7fffffffu;
      if ((b >> 20) == (pfx1 >> 20)) atomicAdd(&lh[(b >> 9) & 0x7ffu], 1u);
    }
  }
  __syncthreads();

  unsigned sum = 0;
  #pragma unroll
  for (int i = 0; i < 8; ++i) sum += lh[t*8 + i];
  part[t] = sum;
  __syncthreads();
  if (t == 0) {
    const unsigned kr = krem1[q];
    unsigned cum = 0; int sc = 0;
    for (int c = 255; c >= 0; --c) {
      if (cum + part[c] >= kr) { sc = c; break; }
      cum += part[c];
    }
    unsigned cum2 = cum; int sb = sc*8;
    for (int b = sc*8 + 7; b >= sc*8; --b) {
      if (cum2 + lh[b] >= kr) { sb = b; break; }
      cum2 += lh[b];
    }
    sh_pfx2 = pfx1 | (((unsigned)sb) << 9);
    sh_kr2  = kr - cum2;
  }
  __syncthreads();
  const unsigned pfx2 = sh_pfx2;

  for (int i = t; i < 512; i += 256) lh[i] = 0;
  __syncthreads();
  if (ok) {
    for (unsigned i = t; i < n; i += 256) {
      const unsigned b = cq[i];
      if ((b >> 9) == (pfx2 >> 9)) atomicAdd(&lh[b & 0x1ffu], 1u);
    }
  } else {
    for (int i = t; i < NPIX; i += 256) {
      const unsigned b = __float_as_uint(sq[i]) & 0x7fffffffu;
      if ((b >> 9) == (pfx2 >> 9)) atomicAdd(&lh[b & 0x1ffu], 1u);
    }
  }
  __syncthreads();

  part[t] = lh[2*t] + lh[2*t + 1];
  __syncthreads();
  if (t == 0) {
    const unsigned kr = sh_kr2;
    unsigned cum = 0; int sc = 0;
    for (int c = 255; c >= 0; --c) {
      if (cum + part[c] >= kr) { sc = c; break; }
      cum += part[c];
    }
    unsigned cum2 = cum; int sb = 2*sc;
    for (int b = 2*sc + 1; b >= 2*sc; --b) {
      if (cum2 + lh[b] >= kr) { sb = b; break; }
      cum2 += lh[b];
    }
    thb[q] = pfx2 | (unsigned)sb;
  }
}

// ===========================================================================
// Backward: per strip, for each filter stage thresholded sim_f (coalesced
// float4, threshold applied per component), row-streaming fp32 conv,
// accumulate across filters in regs, single write of out.
// ===========================================================================
__global__ __launch_bounds__(512, 2) void bwd_all(
    const float* __restrict__ sims,
    const float* __restrict__ w3, const float* __restrict__ w5,
    const float* __restrict__ w7,
    const unsigned* __restrict__ thb, float* __restrict__ out)
{
  __shared__ float xt[TR][LSTR];
  __shared__ float wsm[49];

  const int tid = threadIdx.x;
  const int s  = blockIdx.y;
  const int by = blockIdx.x * ROWS;
  const int tx = tid;
  const float* const wp[NF] = {w3, w5, w7};

  // zero x-halo pads once (never overwritten by staging)
  if (tid < TR*8) {
    const int r = tid >> 3, c = tid & 7;
    xt[r][(c < 4) ? c : 512 + c] = 0.0f;
  }

  float acc[ROWS];
  #pragma unroll
  for (int r = 0; r < ROWS; ++r) acc[r] = 0.0f;

  #pragma unroll
  for (int f = 0; f < NF; ++f) {
    __syncthreads();                    // pads done / prev conv done
    if (tid < 49) wsm[tid] = (tid < (3+2*f)*(3+2*f)) ? wp[f][tid] : 0.0f;
    const unsigned th = thb[f*NSAMP + s];
    const float* __restrict__ ss = sims + ((size_t)f*NSAMP + s)*NPIX;

    for (int idx = tid; idx < TR*128; idx += 512) {
      const int r = idx >> 7, c4 = idx & 127;
      const int gy = by + r - HALO;
      float4 v = make_float4(0.f, 0.f, 0.f, 0.f);
      if (gy >= 0 && gy < HW) {
        v = ((const float4*)(ss + (size_t)gy*HW))[c4];
        if ((__float_as_uint(v.x) & 0x7fffffffu) < th) v.x = 0.0f;
        if ((__float_as_uint(v.y) & 0x7fffffffu) < th) v.y = 0.0f;
        if ((__float_as_uint(v.z) & 0x7fffffffu) < th) v.z = 0.0f;
        if ((__float_as_uint(v.w) & 0x7fffffffu) < th) v.w = 0.0f;
      }
      *(float4*)&xt[r][4 + 4*c4] = v;
    }
    __syncthreads();

    if (f == 0)      conv_rows_f32<3>(xt, wsm, tx, acc);
    else if (f == 1) conv_rows_f32<5>(xt, wsm, tx, acc);
    else             conv_rows_f32<7>(xt, wsm, tx, acc);
  }

  float* __restrict__ oo = out + (size_t)s*NPIX + (size_t)by*HW + tx;
  #pragma unroll
  for (int r = 0; r < ROWS; ++r)
    oo[(size_t)r*HW] = acc[r];
}

// ===========================================================================
extern "C" void kernel_launch(void* const* d_in, const int* in_sizes, int n_in,
                              void* d_out, int out_size, void* d_ws, size_t ws_size,
                              hipStream_t stream)
{
  const float* x  = (const float*)d_in[0];
  const float* w3 = (const float*)d_in[1];
  const float* w5 = (const float*)d_in[2];
  const float* w7 = (const float*)d_in[3];
  float* out = (float*)d_out;
  char* ws = (char*)d_ws;

  const size_t SIMS_B = (size_t)NF*NSAMP*NPIX*sizeof(float);   // 192 MB
  const size_t H1_B   = (size_t)NQ*2048*sizeof(unsigned);      // 1.5 MB
  const size_t CNT_B  = (size_t)NQ*CPAD*sizeof(unsigned);      // 24 KB

  float*    sims    = (float*)ws;
  unsigned* hist1   = (unsigned*)(ws + SIMS_B);
  unsigned* cntp    = hist1 + (size_t)NQ*2048;
  unsigned* prefix1 = cntp + (size_t)NQ*CPAD;
  unsigned* krem1   = prefix1 + NQ;
  unsigned* thb     = krem1 + NQ;
  unsigned* cand    = thb + NQ + NQ;   // spare NQ gap

  // zero hist1 + cntp (contiguous)
  hipMemsetAsync(hist1, 0, H1_B + CNT_B, stream);

  dim3 sb512(512, 1, 1), sg(HW/ROWS, NSAMP, 1);
  fwd_all<<<sg, sb512, 0, stream>>>(x, w3, w5, w7, sims, hist1);
  scan1_all<<<NQ, 256, 0, stream>>>(hist1, prefix1, krem1);
  dim3 rg(NPIX/4096, NQ, 1);
  refine2_all<<<rg, dim3(256,1,1), 0, stream>>>(sims, prefix1, cntp, cand);
  sel23_all<<<NQ, 256, 0, stream>>>(prefix1, krem1, cntp, cand, sims, thb);
  bwd_all<<<sg, sb512, 0, stream>>>(sims, w3, w5, w7, thb, out);
}